// Round 2
// baseline (155.644 us; speedup 1.0000x reference)
//
#include <hip/hip_runtime.h>

// KL( N(pm, ps^2) || N(qm, qs^2) ) elementwise over [32,128,32,64],
// sum over (N,D), mean over (B,L)  ==  sum_all(kl_elem) / (B*L).
// kl_elem = 0.5*(r^2 + d^2 - 1) - log(r),  r = ps/qs, d = (qm-pm)/qs.

constexpr int TOTAL  = 32 * 128 * 32 * 64;   // 8388608 elements
constexpr int N4     = TOTAL / 4;            // 2097152 float4 per input
constexpr int BLOCK  = 256;
constexpr int GRID   = 2048;
constexpr int STRIDE = GRID * BLOCK;         // 524288
constexpr int PT     = N4 / STRIDE;          // 4 float4s per thread, exact
constexpr float INV_BL = 1.0f / (32.0f * 128.0f);

static_assert(PT * STRIDE == N4, "exact tiling");

__device__ __forceinline__ float kl_elem(float a, float b, float c, float d) {
    // a=prior_mu b=prior_sigma c=post_mu d=post_sigma
    float inv = __builtin_amdgcn_rcpf(d);     // v_rcp_f32, ~1ulp
    float r   = b * inv;
    float df  = (c - a) * inv;
    return 0.5f * (r * r + df * df - 1.0f) - __logf(r);
}

__device__ __forceinline__ float kl_4(float4 a, float4 b, float4 c, float4 d) {
    return kl_elem(a.x, b.x, c.x, d.x) + kl_elem(a.y, b.y, c.y, d.y)
         + kl_elem(a.z, b.z, c.z, d.z) + kl_elem(a.w, b.w, c.w, d.w);
}

__global__ __launch_bounds__(BLOCK) void kl_partial_kernel(
    const float4* __restrict__ pm, const float4* __restrict__ ps,
    const float4* __restrict__ qm, const float4* __restrict__ qs,
    float* __restrict__ partial)
{
    const int tid = blockIdx.x * BLOCK + threadIdx.x;

    // Issue ALL 16 loads up front — 16 independent vmem ops in flight,
    // then consume in issue order so the compiler uses partial vmcnt waits.
    float4 A[PT], Bv[PT], C[PT], Dv[PT];
    #pragma unroll
    for (int j = 0; j < PT; ++j) A[j]  = pm[tid + j * STRIDE];
    #pragma unroll
    for (int j = 0; j < PT; ++j) Bv[j] = ps[tid + j * STRIDE];
    #pragma unroll
    for (int j = 0; j < PT; ++j) C[j]  = qm[tid + j * STRIDE];
    #pragma unroll
    for (int j = 0; j < PT; ++j) Dv[j] = qs[tid + j * STRIDE];

    float acc0 = kl_4(A[0], Bv[0], C[0], Dv[0]);
    float acc1 = kl_4(A[1], Bv[1], C[1], Dv[1]);
    float acc2 = kl_4(A[2], Bv[2], C[2], Dv[2]);
    float acc3 = kl_4(A[3], Bv[3], C[3], Dv[3]);
    float acc = (acc0 + acc1) + (acc2 + acc3);

    // wave-64 reduction
    #pragma unroll
    for (int off = 32; off > 0; off >>= 1)
        acc += __shfl_down(acc, off, 64);

    __shared__ float smem[BLOCK / 64];
    const int lane = threadIdx.x & 63;
    const int wid  = threadIdx.x >> 6;
    if (lane == 0) smem[wid] = acc;
    __syncthreads();

    if (threadIdx.x == 0) {
        float t = 0.0f;
        #pragma unroll
        for (int w = 0; w < BLOCK / 64; ++w) t += smem[w];
        partial[blockIdx.x] = t;
    }
}

__global__ __launch_bounds__(BLOCK) void kl_final_kernel(
    const float* __restrict__ partial, float* __restrict__ out)
{
    float acc = 0.0f;
    for (int i = threadIdx.x; i < GRID; i += BLOCK)
        acc += partial[i];

    #pragma unroll
    for (int off = 32; off > 0; off >>= 1)
        acc += __shfl_down(acc, off, 64);

    __shared__ float smem[BLOCK / 64];
    const int lane = threadIdx.x & 63;
    const int wid  = threadIdx.x >> 6;
    if (lane == 0) smem[wid] = acc;
    __syncthreads();

    if (threadIdx.x == 0) {
        float t = 0.0f;
        #pragma unroll
        for (int w = 0; w < BLOCK / 64; ++w) t += smem[w];
        out[0] = t * INV_BL;
    }
}

extern "C" void kernel_launch(void* const* d_in, const int* in_sizes, int n_in,
                              void* d_out, int out_size, void* d_ws, size_t ws_size,
                              hipStream_t stream) {
    const float4* pm = (const float4*)d_in[0];  // prior_mu
    const float4* ps = (const float4*)d_in[1];  // prior_sigma
    const float4* qm = (const float4*)d_in[2];  // post_mu
    const float4* qs = (const float4*)d_in[3];  // post_sigma
    float* partial = (float*)d_ws;              // GRID floats = 8 KiB scratch
    float* out     = (float*)d_out;

    kl_partial_kernel<<<GRID, BLOCK, 0, stream>>>(pm, ps, qm, qs, partial);
    kl_final_kernel<<<1, BLOCK, 0, stream>>>(partial, out);
}

// Round 3
// 152.944 us; speedup vs baseline: 1.0177x; 1.0177x over previous
//
#include <hip/hip_runtime.h>

// KL( N(pm, ps^2) || N(qm, qs^2) ) elementwise over [32,128,32,64],
// sum over (N,D), mean over (B,L)  ==  sum_all(kl_elem) / (B*L).
// kl_elem = 0.5*(r^2 + d^2 - 1) - log(r),  r = ps/qs, d = (qm-pm)/qs.

constexpr int TOTAL  = 32 * 128 * 32 * 64;   // 8388608 elements
constexpr int N4     = TOTAL / 4;            // 2097152 float4 per input
constexpr int BLOCK  = 256;
constexpr int GRID   = 2048;                 // 8 blocks/CU, exactly fills 2048 thr/CU
constexpr int TILE4  = N4 / GRID;            // 1024 float4 per block per array (16 KB)
constexpr float INV_BL = 1.0f / (32.0f * 128.0f);

static_assert(TILE4 == 4 * BLOCK, "depth-4 k loop, exact");

__device__ __forceinline__ float kl_elem(float a, float b, float c, float d) {
    float inv = __builtin_amdgcn_rcpf(d);     // v_rcp_f32, ~1ulp (tolerance is 2%)
    float r   = b * inv;
    float df  = (c - a) * inv;
    return 0.5f * (r * r + df * df - 1.0f) - __logf(r);
}

__device__ __forceinline__ float kl_4(float4 a, float4 b, float4 c, float4 d) {
    return (kl_elem(a.x, b.x, c.x, d.x) + kl_elem(a.y, b.y, c.y, d.y))
         + (kl_elem(a.z, b.z, c.z, d.z) + kl_elem(a.w, b.w, c.w, d.w));
}

__global__ __launch_bounds__(BLOCK) void kl_partial_kernel(
    const float4* __restrict__ pm, const float4* __restrict__ ps,
    const float4* __restrict__ qm, const float4* __restrict__ qs,
    float* __restrict__ partial)
{
    // Contiguous tile: block b owns float4 range [b*1024, (b+1)*1024) of each
    // array -> 4 distinct 2MB pages per block total (TLB-friendly), linear sweep.
    const int i0 = blockIdx.x * TILE4 + threadIdx.x;
    const int i1 = i0 + BLOCK;
    const int i2 = i0 + 2 * BLOCK;
    const int i3 = i0 + 3 * BLOCK;

    // Depth-2 register pipeline. Issue batch k+1's loads BEFORE consuming
    // batch k, reuse batch slots only after consumption (no WAR stall).
    // First use of each batch should wait at vmcnt(4), not vmcnt(0).
    float4 a0 = pm[i0], b0 = ps[i0], c0 = qm[i0], d0 = qs[i0];
    float4 a1 = pm[i1], b1 = ps[i1], c1 = qm[i1], d1 = qs[i1];

    float accA = kl_4(a0, b0, c0, d0);        // waits on batch0 only
    a0 = pm[i2]; b0 = ps[i2]; c0 = qm[i2]; d0 = qs[i2];

    float accB = kl_4(a1, b1, c1, d1);        // waits on batch1 only
    a1 = pm[i3]; b1 = ps[i3]; c1 = qm[i3]; d1 = qs[i3];

    accA += kl_4(a0, b0, c0, d0);
    accB += kl_4(a1, b1, c1, d1);
    float acc = accA + accB;

    // wave-64 reduction
    #pragma unroll
    for (int off = 32; off > 0; off >>= 1)
        acc += __shfl_down(acc, off, 64);

    __shared__ float smem[BLOCK / 64];
    const int lane = threadIdx.x & 63;
    const int wid  = threadIdx.x >> 6;
    if (lane == 0) smem[wid] = acc;
    __syncthreads();

    if (threadIdx.x == 0) {
        float t = 0.0f;
        #pragma unroll
        for (int w = 0; w < BLOCK / 64; ++w) t += smem[w];
        partial[blockIdx.x] = t;
    }
}

__global__ __launch_bounds__(BLOCK) void kl_final_kernel(
    const float* __restrict__ partial, float* __restrict__ out)
{
    float acc = 0.0f;
    for (int i = threadIdx.x; i < GRID; i += BLOCK)
        acc += partial[i];

    #pragma unroll
    for (int off = 32; off > 0; off >>= 1)
        acc += __shfl_down(acc, off, 64);

    __shared__ float smem[BLOCK / 64];
    const int lane = threadIdx.x & 63;
    const int wid  = threadIdx.x >> 6;
    if (lane == 0) smem[wid] = acc;
    __syncthreads();

    if (threadIdx.x == 0) {
        float t = 0.0f;
        #pragma unroll
        for (int w = 0; w < BLOCK / 64; ++w) t += smem[w];
        out[0] = t * INV_BL;
    }
}

extern "C" void kernel_launch(void* const* d_in, const int* in_sizes, int n_in,
                              void* d_out, int out_size, void* d_ws, size_t ws_size,
                              hipStream_t stream) {
    const float4* pm = (const float4*)d_in[0];  // prior_mu
    const float4* ps = (const float4*)d_in[1];  // prior_sigma
    const float4* qm = (const float4*)d_in[2];  // post_mu
    const float4* qs = (const float4*)d_in[3];  // post_sigma
    float* partial = (float*)d_ws;              // GRID floats = 8 KiB scratch
    float* out     = (float*)d_out;

    kl_partial_kernel<<<GRID, BLOCK, 0, stream>>>(pm, ps, qm, qs, partial);
    kl_final_kernel<<<1, BLOCK, 0, stream>>>(partial, out);
}

// Round 4
// 149.529 us; speedup vs baseline: 1.0409x; 1.0228x over previous
//
#include <hip/hip_runtime.h>

// KL( N(pm, ps^2) || N(qm, qs^2) ) elementwise over [32,128,32,64],
// sum over (N,D), mean over (B,L)  ==  sum_all(kl_elem) / (B*L).
// kl_elem = 0.5*(r^2 + d^2 - 1) - log(r),  r = ps/qs, d = (qm-pm)/qs.
//
// R3 evidence: runtime ~44us invariant across load structures AND with fully
// L3-resident data => bound by per-workgroup dispatch overhead (GRID=2048).
// This round: 4x fewer, 4x fatter blocks. GRID=512 x BLOCK=1024.

constexpr int TOTAL  = 32 * 128 * 32 * 64;   // 8388608 elements
constexpr int N4     = TOTAL / 4;            // 2097152 float4 per input
constexpr int BLOCK  = 1024;                 // 16 waves/block
constexpr int GRID   = 512;                  // 2 blocks/CU -> 32 waves/CU
constexpr int TILE4  = N4 / GRID;            // 4096 float4 per block per array
constexpr float INV_BL = 1.0f / (32.0f * 128.0f);

static_assert(TILE4 == 4 * BLOCK, "depth-4 per-thread, exact");

__device__ __forceinline__ float kl_elem(float a, float b, float c, float d) {
    float inv = __builtin_amdgcn_rcpf(d);     // v_rcp_f32, ~1ulp (tolerance is 2%)
    float r   = b * inv;
    float df  = (c - a) * inv;
    return 0.5f * (r * r + df * df - 1.0f) - __logf(r);
}

__device__ __forceinline__ float kl_4(float4 a, float4 b, float4 c, float4 d) {
    return (kl_elem(a.x, b.x, c.x, d.x) + kl_elem(a.y, b.y, c.y, d.y))
         + (kl_elem(a.z, b.z, c.z, d.z) + kl_elem(a.w, b.w, c.w, d.w));
}

__global__ __launch_bounds__(BLOCK) void kl_partial_kernel(
    const float4* __restrict__ pm, const float4* __restrict__ ps,
    const float4* __restrict__ qm, const float4* __restrict__ qs,
    float* __restrict__ partial)
{
    // Contiguous tile: block b owns float4 range [b*4096, (b+1)*4096) of each
    // array (64 KB per array), linear coalesced sweep.
    const int i0 = blockIdx.x * TILE4 + threadIdx.x;
    const int i1 = i0 + BLOCK;
    const int i2 = i0 + 2 * BLOCK;
    const int i3 = i0 + 3 * BLOCK;

    // Depth-2 register pipeline: issue batch k+1's loads before consuming k.
    float4 a0 = pm[i0], b0 = ps[i0], c0 = qm[i0], d0 = qs[i0];
    float4 a1 = pm[i1], b1 = ps[i1], c1 = qm[i1], d1 = qs[i1];

    float accA = kl_4(a0, b0, c0, d0);
    a0 = pm[i2]; b0 = ps[i2]; c0 = qm[i2]; d0 = qs[i2];

    float accB = kl_4(a1, b1, c1, d1);
    a1 = pm[i3]; b1 = ps[i3]; c1 = qm[i3]; d1 = qs[i3];

    accA += kl_4(a0, b0, c0, d0);
    accB += kl_4(a1, b1, c1, d1);
    float acc = accA + accB;

    // wave-64 reduction
    #pragma unroll
    for (int off = 32; off > 0; off >>= 1)
        acc += __shfl_down(acc, off, 64);

    __shared__ float smem[BLOCK / 64];        // 16 waves
    const int lane = threadIdx.x & 63;
    const int wid  = threadIdx.x >> 6;
    if (lane == 0) smem[wid] = acc;
    __syncthreads();

    if (threadIdx.x == 0) {
        float t = 0.0f;
        #pragma unroll
        for (int w = 0; w < BLOCK / 64; ++w) t += smem[w];
        partial[blockIdx.x] = t;
    }
}

__global__ __launch_bounds__(256) void kl_final_kernel(
    const float* __restrict__ partial, float* __restrict__ out)
{
    float acc = 0.0f;
    for (int i = threadIdx.x; i < GRID; i += 256)
        acc += partial[i];

    #pragma unroll
    for (int off = 32; off > 0; off >>= 1)
        acc += __shfl_down(acc, off, 64);

    __shared__ float smem[4];
    const int lane = threadIdx.x & 63;
    const int wid  = threadIdx.x >> 6;
    if (lane == 0) smem[wid] = acc;
    __syncthreads();

    if (threadIdx.x == 0) {
        float t = 0.0f;
        #pragma unroll
        for (int w = 0; w < 4; ++w) t += smem[w];
        out[0] = t * INV_BL;
    }
}

extern "C" void kernel_launch(void* const* d_in, const int* in_sizes, int n_in,
                              void* d_out, int out_size, void* d_ws, size_t ws_size,
                              hipStream_t stream) {
    const float4* pm = (const float4*)d_in[0];  // prior_mu
    const float4* ps = (const float4*)d_in[1];  // prior_sigma
    const float4* qm = (const float4*)d_in[2];  // post_mu
    const float4* qs = (const float4*)d_in[3];  // post_sigma
    float* partial = (float*)d_ws;              // GRID floats = 2 KiB scratch
    float* out     = (float*)d_out;

    kl_partial_kernel<<<GRID, BLOCK, 0, stream>>>(pm, ps, qm, qs, partial);
    kl_final_kernel<<<1, 256, 0, stream>>>(partial, out);
}

// Round 5
// 149.121 us; speedup vs baseline: 1.0437x; 1.0027x over previous
//
#include <hip/hip_runtime.h>

// KL( N(pm, ps^2) || N(qm, qs^2) ) over [32,128,32,64], sum/(B*L).
// kl_elem = 0.5*(r^2 + d^2 - 1) - log(r),  r = ps/qs, d = (qm-pm)/qs.
//
// R4 evidence: ~42us invariant across load structure, grid shape, occupancy.
// Delivered read BW pinned at ~3.2 TB/s while fill writes 6.4 TB/s.
// This round: bypass the VGPR/L1 load-return path entirely with
// global_load_lds (direct-to-LDS DMA, 16B/lane), wave-private tiles.

constexpr int TOTAL  = 32 * 128 * 32 * 64;   // 8388608 elements
constexpr int N4     = TOTAL / 4;            // 2097152 float4 per array
constexpr int BLOCK  = 256;                  // 4 waves
constexpr int GRID   = 2048;
constexpr int TILE4  = N4 / GRID;            // 1024 float4 per array per block
constexpr int CHUNKS = TILE4 / 64;           // 16 chunks of 64 float4 (1 KB each)
constexpr int WAVES  = BLOCK / 64;           // 4
constexpr int CPW    = CHUNKS / WAVES;       // 4 chunks per wave per array
constexpr float INV_BL = 1.0f / (32.0f * 128.0f);

static_assert(CPW * WAVES == CHUNKS, "exact");

#define GLOBAL_AS __attribute__((address_space(1)))
#define LDS_AS    __attribute__((address_space(3)))

__device__ __forceinline__ void load_lds16(const void* g, void* l) {
    // 64 lanes x 16 B: global gptr+lane*16 -> LDS base(uniform)+lane*16
    __builtin_amdgcn_global_load_lds((const GLOBAL_AS void*)g,
                                     (LDS_AS void*)l, 16, 0, 0);
}

__device__ __forceinline__ float kl_elem(float a, float b, float c, float d) {
    float inv = __builtin_amdgcn_rcpf(d);     // v_rcp_f32, ~1ulp (tol is 2%)
    float r   = b * inv;
    float df  = (c - a) * inv;
    return 0.5f * (r * r + df * df - 1.0f) - __logf(r);
}

__device__ __forceinline__ float kl_4(float4 a, float4 b, float4 c, float4 d) {
    return (kl_elem(a.x, b.x, c.x, d.x) + kl_elem(a.y, b.y, c.y, d.y))
         + (kl_elem(a.z, b.z, c.z, d.z) + kl_elem(a.w, b.w, c.w, d.w));
}

__global__ __launch_bounds__(BLOCK) void kl_partial_kernel(
    const float4* __restrict__ pm, const float4* __restrict__ ps,
    const float4* __restrict__ qm, const float4* __restrict__ qs,
    float* __restrict__ partial)
{
    __shared__ float4 lds[4][TILE4];          // exactly 64 KB -> 2 blocks/CU

    const int lane = threadIdx.x & 63;
    const int wid  = threadIdx.x >> 6;
    const int base = blockIdx.x * TILE4;

    const float4* __restrict__ arr[4] = {pm, ps, qm, qs};

    // Stage: wave w DMAs its own chunks [w*CPW, (w+1)*CPW) of all 4 arrays.
    // 16 x 1KB wave-transfers in flight per wave, zero VGPR cost.
    #pragma unroll
    for (int k = 0; k < CPW; ++k) {
        const int c = wid * CPW + k;
        #pragma unroll
        for (int a = 0; a < 4; ++a) {
            load_lds16(arr[a] + base + c * 64 + lane, &lds[a][c * 64]);
        }
    }
    asm volatile("s_waitcnt vmcnt(0)" ::: "memory");

    // Consume wave-private chunks: lane L of wave w reads float4 c*64+L.
    float acc = 0.0f;
    #pragma unroll
    for (int k = 0; k < CPW; ++k) {
        const int i = (wid * CPW + k) * 64 + lane;
        acc += kl_4(lds[0][i], lds[1][i], lds[2][i], lds[3][i]);
    }

    // wave-64 reduction
    #pragma unroll
    for (int off = 32; off > 0; off >>= 1)
        acc += __shfl_down(acc, off, 64);

    // block reduction — reuse staging LDS after a barrier
    __syncthreads();
    float* red = (float*)&lds[0][0];
    if (lane == 0) red[wid] = acc;
    __syncthreads();

    if (threadIdx.x == 0) {
        float t = 0.0f;
        #pragma unroll
        for (int w = 0; w < WAVES; ++w) t += red[w];
        partial[blockIdx.x] = t;
    }
}

__global__ __launch_bounds__(256) void kl_final_kernel(
    const float* __restrict__ partial, float* __restrict__ out)
{
    float acc = 0.0f;
    for (int i = threadIdx.x; i < GRID; i += 256)
        acc += partial[i];

    #pragma unroll
    for (int off = 32; off > 0; off >>= 1)
        acc += __shfl_down(acc, off, 64);

    __shared__ float smem[4];
    const int lane = threadIdx.x & 63;
    const int wid  = threadIdx.x >> 6;
    if (lane == 0) smem[wid] = acc;
    __syncthreads();

    if (threadIdx.x == 0) {
        float t = 0.0f;
        #pragma unroll
        for (int w = 0; w < 4; ++w) t += smem[w];
        out[0] = t * INV_BL;
    }
}

extern "C" void kernel_launch(void* const* d_in, const int* in_sizes, int n_in,
                              void* d_out, int out_size, void* d_ws, size_t ws_size,
                              hipStream_t stream) {
    const float4* pm = (const float4*)d_in[0];  // prior_mu
    const float4* ps = (const float4*)d_in[1];  // prior_sigma
    const float4* qm = (const float4*)d_in[2];  // post_mu
    const float4* qs = (const float4*)d_in[3];  // post_sigma
    float* partial = (float*)d_ws;              // GRID floats = 8 KiB scratch
    float* out     = (float*)d_out;

    kl_partial_kernel<<<GRID, BLOCK, 0, stream>>>(pm, ps, qm, qs, partial);
    kl_final_kernel<<<1, 256, 0, stream>>>(partial, out);
}

// Round 7
// 143.747 us; speedup vs baseline: 1.0828x; 1.0374x over previous
//
#include <hip/hip_runtime.h>

// KL( N(pm, ps^2) || N(qm, qs^2) ) over [32,128,32,64], sum/(B*L).
// kl_elem = 0.5*(r^2 + d^2 - 1) - log(r),  r = ps/qs, d = (qm-pm)/qs.
//
// R5 evidence: 42us invariant across 5 structures incl. LDS-DMA, and even
// with data fully L3-resident. Delivered reads pinned at 3.2 TB/s
// (= 5.2 B/cyc/CU) while writes hit 6.6 TB/s. Theory: per-CU L1 line-fill
// (MSHR) throughput clamps streaming (zero-reuse) reads.
// Single variable this round: NON-TEMPORAL loads (nt bit, no L1 allocate).
// R6 fix: __builtin_nontemporal_load needs a native vector type, not
// HIP_vector_type — use ext_vector_type(4) float.

constexpr int TOTAL  = 32 * 128 * 32 * 64;   // 8388608 elements
constexpr int N4     = TOTAL / 4;            // 2097152 float4 per array
constexpr int BLOCK  = 256;
constexpr int GRID   = 2048;
constexpr int TILE4  = N4 / GRID;            // 1024 float4 per array per block
constexpr float INV_BL = 1.0f / (32.0f * 128.0f);

static_assert(TILE4 == 4 * BLOCK, "depth-4 per-thread, exact");

typedef float f4 __attribute__((ext_vector_type(4)));

__device__ __forceinline__ f4 ntload(const float4* p) {
    return __builtin_nontemporal_load((const f4*)p);
}

__device__ __forceinline__ float kl_elem(float a, float b, float c, float d) {
    float inv = __builtin_amdgcn_rcpf(d);     // v_rcp_f32, ~1ulp (tol is 2%)
    float r   = b * inv;
    float df  = (c - a) * inv;
    return 0.5f * (r * r + df * df - 1.0f) - __logf(r);
}

__device__ __forceinline__ float kl_4(f4 a, f4 b, f4 c, f4 d) {
    return (kl_elem(a.x, b.x, c.x, d.x) + kl_elem(a.y, b.y, c.y, d.y))
         + (kl_elem(a.z, b.z, c.z, d.z) + kl_elem(a.w, b.w, c.w, d.w));
}

__global__ __launch_bounds__(BLOCK) void kl_partial_kernel(
    const float4* __restrict__ pm, const float4* __restrict__ ps,
    const float4* __restrict__ qm, const float4* __restrict__ qs,
    float* __restrict__ partial)
{
    // Contiguous per-block tile, linear coalesced sweep.
    const int i0 = blockIdx.x * TILE4 + threadIdx.x;
    const int i1 = i0 + BLOCK;
    const int i2 = i0 + 2 * BLOCK;
    const int i3 = i0 + 3 * BLOCK;

    // Depth-2 register pipeline; ALL loads non-temporal (L1 bypass).
    f4 a0 = ntload(pm + i0), b0 = ntload(ps + i0),
       c0 = ntload(qm + i0), d0 = ntload(qs + i0);
    f4 a1 = ntload(pm + i1), b1 = ntload(ps + i1),
       c1 = ntload(qm + i1), d1 = ntload(qs + i1);

    float accA = kl_4(a0, b0, c0, d0);
    a0 = ntload(pm + i2); b0 = ntload(ps + i2);
    c0 = ntload(qm + i2); d0 = ntload(qs + i2);

    float accB = kl_4(a1, b1, c1, d1);
    a1 = ntload(pm + i3); b1 = ntload(ps + i3);
    c1 = ntload(qm + i3); d1 = ntload(qs + i3);

    accA += kl_4(a0, b0, c0, d0);
    accB += kl_4(a1, b1, c1, d1);
    float acc = accA + accB;

    // wave-64 reduction
    #pragma unroll
    for (int off = 32; off > 0; off >>= 1)
        acc += __shfl_down(acc, off, 64);

    __shared__ float smem[BLOCK / 64];
    const int lane = threadIdx.x & 63;
    const int wid  = threadIdx.x >> 6;
    if (lane == 0) smem[wid] = acc;
    __syncthreads();

    if (threadIdx.x == 0) {
        float t = 0.0f;
        #pragma unroll
        for (int w = 0; w < BLOCK / 64; ++w) t += smem[w];
        partial[blockIdx.x] = t;
    }
}

__global__ __launch_bounds__(256) void kl_final_kernel(
    const float* __restrict__ partial, float* __restrict__ out)
{
    float acc = 0.0f;
    for (int i = threadIdx.x; i < GRID; i += 256)
        acc += partial[i];

    #pragma unroll
    for (int off = 32; off > 0; off >>= 1)
        acc += __shfl_down(acc, off, 64);

    __shared__ float smem[4];
    const int lane = threadIdx.x & 63;
    const int wid  = threadIdx.x >> 6;
    if (lane == 0) smem[wid] = acc;
    __syncthreads();

    if (threadIdx.x == 0) {
        float t = 0.0f;
        #pragma unroll
        for (int w = 0; w < 4; ++w) t += smem[w];
        out[0] = t * INV_BL;
    }
}

extern "C" void kernel_launch(void* const* d_in, const int* in_sizes, int n_in,
                              void* d_out, int out_size, void* d_ws, size_t ws_size,
                              hipStream_t stream) {
    const float4* pm = (const float4*)d_in[0];  // prior_mu
    const float4* ps = (const float4*)d_in[1];  // prior_sigma
    const float4* qm = (const float4*)d_in[2];  // post_mu
    const float4* qs = (const float4*)d_in[3];  // post_sigma
    float* partial = (float*)d_ws;              // GRID floats = 8 KiB scratch
    float* out     = (float*)d_out;

    kl_partial_kernel<<<GRID, BLOCK, 0, stream>>>(pm, ps, qm, qs, partial);
    kl_final_kernel<<<1, 256, 0, stream>>>(partial, out);
}

// Round 8
// 142.761 us; speedup vs baseline: 1.0902x; 1.0069x over previous
//
#include <hip/hip_runtime.h>

// KL( N(pm, ps^2) || N(qm, qs^2) ) over [32,128,32,64], sum/(B*L).
// kl_elem = 0.5*(r^2 + d^2 - 1) - log(r),  r = ps/qs, d = (qm-pm)/qs.
//
// R7 evidence: nt (L1-bypass) loads dropped kl_partial below the 40us
// harness fills (42 -> <40us); bench 149 -> 143.7. L1 line-fill clamp
// confirmed as (part of) the streaming-read limiter.
// This round: nt + ALL 16 loads issued up front, pinned with
// sched_barrier(0) so the scheduler can't sink loads to uses (R2 failure
// mode). Consume in issue order -> partial vmcnt waits.

constexpr int TOTAL  = 32 * 128 * 32 * 64;   // 8388608 elements
constexpr int N4     = TOTAL / 4;            // 2097152 float4 per array
constexpr int BLOCK  = 256;
constexpr int GRID   = 2048;
constexpr int TILE4  = N4 / GRID;            // 1024 float4 per array per block
constexpr float INV_BL = 1.0f / (32.0f * 128.0f);

static_assert(TILE4 == 4 * BLOCK, "depth-4 per-thread, exact");

typedef float f4 __attribute__((ext_vector_type(4)));

__device__ __forceinline__ f4 ntload(const float4* p) {
    return __builtin_nontemporal_load((const f4*)p);
}

__device__ __forceinline__ float kl_elem(float a, float b, float c, float d) {
    float inv = __builtin_amdgcn_rcpf(d);     // v_rcp_f32, ~1ulp (tol is 2%)
    float r   = b * inv;
    float df  = (c - a) * inv;
    return 0.5f * (r * r + df * df - 1.0f) - __logf(r);
}

__device__ __forceinline__ float kl_4(f4 a, f4 b, f4 c, f4 d) {
    return (kl_elem(a.x, b.x, c.x, d.x) + kl_elem(a.y, b.y, c.y, d.y))
         + (kl_elem(a.z, b.z, c.z, d.z) + kl_elem(a.w, b.w, c.w, d.w));
}

__global__ __launch_bounds__(BLOCK) void kl_partial_kernel(
    const float4* __restrict__ pm, const float4* __restrict__ ps,
    const float4* __restrict__ qm, const float4* __restrict__ qs,
    float* __restrict__ partial)
{
    // Contiguous per-block tile, linear coalesced sweep.
    const int i0 = blockIdx.x * TILE4 + threadIdx.x;
    const int i1 = i0 + BLOCK;
    const int i2 = i0 + 2 * BLOCK;
    const int i3 = i0 + 3 * BLOCK;

    // Issue ALL 16 nt loads, batch-major so consumption order == issue order.
    f4 a0 = ntload(pm + i0), b0 = ntload(ps + i0),
       c0 = ntload(qm + i0), d0 = ntload(qs + i0);
    f4 a1 = ntload(pm + i1), b1 = ntload(ps + i1),
       c1 = ntload(qm + i1), d1 = ntload(qs + i1);
    f4 a2 = ntload(pm + i2), b2 = ntload(ps + i2),
       c2 = ntload(qm + i2), d2 = ntload(qs + i2);
    f4 a3 = ntload(pm + i3), b3 = ntload(ps + i3),
       c3 = ntload(qm + i3), d3 = ntload(qs + i3);

    // Hard fence: nothing moves across — loads stay issued up here.
    __builtin_amdgcn_sched_barrier(0);

    float accA = kl_4(a0, b0, c0, d0);   // vmcnt(12)
    float accB = kl_4(a1, b1, c1, d1);   // vmcnt(8)
    accA += kl_4(a2, b2, c2, d2);        // vmcnt(4)
    accB += kl_4(a3, b3, c3, d3);        // vmcnt(0)
    float acc = accA + accB;

    // wave-64 reduction
    #pragma unroll
    for (int off = 32; off > 0; off >>= 1)
        acc += __shfl_down(acc, off, 64);

    __shared__ float smem[BLOCK / 64];
    const int lane = threadIdx.x & 63;
    const int wid  = threadIdx.x >> 6;
    if (lane == 0) smem[wid] = acc;
    __syncthreads();

    if (threadIdx.x == 0) {
        float t = 0.0f;
        #pragma unroll
        for (int w = 0; w < BLOCK / 64; ++w) t += smem[w];
        partial[blockIdx.x] = t;
    }
}

__global__ __launch_bounds__(256) void kl_final_kernel(
    const float* __restrict__ partial, float* __restrict__ out)
{
    float acc = 0.0f;
    for (int i = threadIdx.x; i < GRID; i += 256)
        acc += partial[i];

    #pragma unroll
    for (int off = 32; off > 0; off >>= 1)
        acc += __shfl_down(acc, off, 64);

    __shared__ float smem[4];
    const int lane = threadIdx.x & 63;
    const int wid  = threadIdx.x >> 6;
    if (lane == 0) smem[wid] = acc;
    __syncthreads();

    if (threadIdx.x == 0) {
        float t = 0.0f;
        #pragma unroll
        for (int w = 0; w < 4; ++w) t += smem[w];
        out[0] = t * INV_BL;
    }
}

extern "C" void kernel_launch(void* const* d_in, const int* in_sizes, int n_in,
                              void* d_out, int out_size, void* d_ws, size_t ws_size,
                              hipStream_t stream) {
    const float4* pm = (const float4*)d_in[0];  // prior_mu
    const float4* ps = (const float4*)d_in[1];  // prior_sigma
    const float4* qm = (const float4*)d_in[2];  // post_mu
    const float4* qs = (const float4*)d_in[3];  // post_sigma
    float* partial = (float*)d_ws;              // GRID floats = 8 KiB scratch
    float* out     = (float*)d_out;

    kl_partial_kernel<<<GRID, BLOCK, 0, stream>>>(pm, ps, qm, qs, partial);
    kl_final_kernel<<<1, 256, 0, stream>>>(partial, out);
}

// Round 9
// 141.569 us; speedup vs baseline: 1.0994x; 1.0084x over previous
//
#include <hip/hip_runtime.h>

// KL( N(pm, ps^2) || N(qm, qs^2) ) over [32,128,32,64], sum/(B*L).
// kl_elem = 0.5*(r^2 + d^2 - 1) - log(r),  r = ps/qs, d = (qm-pm)/qs.
//
// R7/R8: nt (L1-bypass) loads moved partial 42 -> ~35-36us (read ~3.8 TB/s).
// This round: double per-wave MLP. GRID=1024, 8 batches/thread -> 32 nt
// loads issued up front (32 KB in flight per wave), pinned by
// sched_barrier(0), consumed in issue order (partial vmcnt waits).

constexpr int TOTAL  = 32 * 128 * 32 * 64;   // 8388608 elements
constexpr int N4     = TOTAL / 4;            // 2097152 float4 per array
constexpr int BLOCK  = 256;
constexpr int GRID   = 1024;
constexpr int TILE4  = N4 / GRID;            // 2048 float4 per array per block
constexpr int PT     = TILE4 / BLOCK;        // 8 batches per thread
constexpr float INV_BL = 1.0f / (32.0f * 128.0f);

static_assert(PT == 8, "depth-8 per-thread, exact");

typedef float f4 __attribute__((ext_vector_type(4)));

__device__ __forceinline__ f4 ntload(const float4* p) {
    return __builtin_nontemporal_load((const f4*)p);
}

__device__ __forceinline__ float kl_elem(float a, float b, float c, float d) {
    float inv = __builtin_amdgcn_rcpf(d);     // v_rcp_f32, ~1ulp (tol is 2%)
    float r   = b * inv;
    float df  = (c - a) * inv;
    return 0.5f * (r * r + df * df - 1.0f) - __logf(r);
}

__device__ __forceinline__ float kl_4(f4 a, f4 b, f4 c, f4 d) {
    return (kl_elem(a.x, b.x, c.x, d.x) + kl_elem(a.y, b.y, c.y, d.y))
         + (kl_elem(a.z, b.z, c.z, d.z) + kl_elem(a.w, b.w, c.w, d.w));
}

__global__ __launch_bounds__(BLOCK) void kl_partial_kernel(
    const float4* __restrict__ pm, const float4* __restrict__ ps,
    const float4* __restrict__ qm, const float4* __restrict__ qs,
    float* __restrict__ partial)
{
    const int base = blockIdx.x * TILE4 + threadIdx.x;

    // Issue ALL 32 nt loads, batch-major (consumption order == issue order).
    f4 A[PT], Bv[PT], C[PT], Dv[PT];
    #pragma unroll
    for (int j = 0; j < PT; ++j) {
        const int i = base + j * BLOCK;
        A[j]  = ntload(pm + i);
        Bv[j] = ntload(ps + i);
        C[j]  = ntload(qm + i);
        Dv[j] = ntload(qs + i);
    }

    // Hard fence: loads stay issued above; consumption below.
    __builtin_amdgcn_sched_barrier(0);

    float accA = 0.0f, accB = 0.0f;
    #pragma unroll
    for (int j = 0; j < PT; j += 2) {
        accA += kl_4(A[j],     Bv[j],     C[j],     Dv[j]);
        accB += kl_4(A[j + 1], Bv[j + 1], C[j + 1], Dv[j + 1]);
    }
    float acc = accA + accB;

    // wave-64 reduction
    #pragma unroll
    for (int off = 32; off > 0; off >>= 1)
        acc += __shfl_down(acc, off, 64);

    __shared__ float smem[BLOCK / 64];
    const int lane = threadIdx.x & 63;
    const int wid  = threadIdx.x >> 6;
    if (lane == 0) smem[wid] = acc;
    __syncthreads();

    if (threadIdx.x == 0) {
        float t = 0.0f;
        #pragma unroll
        for (int w = 0; w < BLOCK / 64; ++w) t += smem[w];
        partial[blockIdx.x] = t;
    }
}

__global__ __launch_bounds__(256) void kl_final_kernel(
    const float* __restrict__ partial, float* __restrict__ out)
{
    float acc = 0.0f;
    for (int i = threadIdx.x; i < GRID; i += 256)
        acc += partial[i];

    #pragma unroll
    for (int off = 32; off > 0; off >>= 1)
        acc += __shfl_down(acc, off, 64);

    __shared__ float smem[4];
    const int lane = threadIdx.x & 63;
    const int wid  = threadIdx.x >> 6;
    if (lane == 0) smem[wid] = acc;
    __syncthreads();

    if (threadIdx.x == 0) {
        float t = 0.0f;
        #pragma unroll
        for (int w = 0; w < 4; ++w) t += smem[w];
        out[0] = t * INV_BL;
    }
}

extern "C" void kernel_launch(void* const* d_in, const int* in_sizes, int n_in,
                              void* d_out, int out_size, void* d_ws, size_t ws_size,
                              hipStream_t stream) {
    const float4* pm = (const float4*)d_in[0];  // prior_mu
    const float4* ps = (const float4*)d_in[1];  // prior_sigma
    const float4* qm = (const float4*)d_in[2];  // post_mu
    const float4* qs = (const float4*)d_in[3];  // post_sigma
    float* partial = (float*)d_ws;              // GRID floats = 4 KiB scratch
    float* out     = (float*)d_out;

    kl_partial_kernel<<<GRID, BLOCK, 0, stream>>>(pm, ps, qm, qs, partial);
    kl_final_kernel<<<1, 256, 0, stream>>>(partial, out);
}